// Round 4
// baseline (372.297 us; speedup 1.0000x reference)
//
#include <hip/hip_runtime.h>
#include <cmath>

// FFTConv via chunked diagonal SSM + MFMA.
//
// y[n] = tanh( sum_{d>=0} k_d u[n-d] (circular) + D*u[n] ),  k_d = Re sum_p bc_p A_p^d.
// Chunk n = c*128 + r (64 chunks):
//   y[c,r]  = sum_j T'[r][j] u[c*128+j] + Re sum_p bc_p A_p^{r+1} sB_p[c]
//   sB[c+1] = A^128 sB[c] + S_in[c],  S_in[c] = sum_j A^{127-j} u[c*128+j]  (GEMM)
// Circular init: 8-chunk (1024-step) warm-up scan, truncation ~|A|^1024 <= 3.4e-5.
//
// R4: (a) prep uses native __cosf/__sinf (was ~120 us of libm trig);
//     (b) main splits each sequence across 2 blocks (32 emit + 8 warm chunks),
//         LDS 21.8 KB -> 7 blocks/CU resident, grid 8192, 40-step scan.

typedef _Float16 half8 __attribute__((ext_vector_type(8)));
typedef _Float16 half4v __attribute__((ext_vector_type(4)));
typedef float floatx16 __attribute__((ext_vector_type(16)));

#define CM 128
#define ROWS 40    // 8 warm + 32 emit chunks staged per block
#define ROWP 136   // padded LDS row stride in halves (272 B, 16B-aligned)
#define A2_BYTES ((size_t)256 * 128 * 256 * 2)
#define W_BYTES  ((size_t)128 * 128 * 2)
#define AM_OFF   (A2_BYTES + W_BYTES)

__device__ __forceinline__ float fast_tanh(float x) {
    float e2 = __expf(2.0f * x);
    return 1.0f - 2.0f / (e2 + 1.0f);   // exact +/-1 at saturation, no NaN
}

__global__ void fftconv_prep(const float* __restrict__ A_re, const float* __restrict__ A_im,
                             const float* __restrict__ BC_re, const float* __restrict__ BC_im,
                             const float* __restrict__ Dv, char* __restrict__ ws) {
    __shared__ float rr[64], th[64], br[64], bi[64];
    __shared__ float kk[CM];
    const int h = blockIdx.x, tid = threadIdx.x;
    if (tid < 64) {
        float x = A_re[tid], y = A_im[tid];
        rr[tid] = log2f(sqrtf(x * x + y * y));   // log2|A|
        th[tid] = atan2f(y, x);                  // arg(A)
        br[tid] = BC_re[h * 64 + tid];
        bi[tid] = BC_im[h * 64 + tid];
    }
    __syncthreads();
    if (tid < CM) {   // kernel taps k_d, d = 0..127
        float d = (float)tid, s = 0.f;
        for (int p = 0; p < 64; ++p) {
            float mag = exp2f(d * rr[p]);
            float ang = d * th[p];
            s += mag * (br[p] * __cosf(ang) - bi[p] * __sinf(ang));
        }
        kk[tid] = s;
    }
    __syncthreads();
    _Float16* A2 = (_Float16*)ws + (size_t)h * 128 * 256;
    const float Dh = Dv[h];
    // G part: A2[r][pc] = pc<64 ? Re(bc_p A^{r+1}) : -Im(bc_p A^{r+1})
    for (int idx = tid; idx < 128 * 128; idx += 256) {
        int r = idx >> 7, pc = idx & 127, p = pc & 63;
        float e = (float)(r + 1);
        float mag = exp2f(e * rr[p]);
        float ang = e * th[p];
        float cr = mag * __cosf(ang), ci = mag * __sinf(ang);
        float val = (pc < 64) ? (br[p] * cr - bi[p] * ci) : -(br[p] * ci + bi[p] * cr);
        A2[r * 256 + pc] = (_Float16)val;
    }
    // T' part: A2[r][128+j] = k_{r-j} (j<=r) + D*(j==r)
    for (int idx = tid; idx < 128 * 128; idx += 256) {
        int r = idx >> 7, j = idx & 127;
        float v = (j <= r) ? kk[r - j] : 0.f;
        if (j == r) v += Dh;
        A2[r * 256 + CM + j] = (_Float16)v;
    }
    if (h == 0) {
        _Float16* W = (_Float16*)(ws + A2_BYTES);   // W[pc][j] = comp(A_p^{127-j})
        for (int idx = tid; idx < 128 * 128; idx += 256) {
            int pc = idx >> 7, j = idx & 127, p = pc & 63;
            float e = (float)(127 - j);
            float mag = exp2f(e * rr[p]);
            float ang = e * th[p];
            float v = (pc < 64) ? mag * __cosf(ang) : mag * __sinf(ang);
            W[pc * 128 + j] = (_Float16)v;
        }
        if (tid < 64) {   // A^128 fp32 for the scan
            float mag = exp2f(128.f * rr[tid]);
            float ang = 128.f * th[tid];
            float* aM = (float*)(ws + AM_OFF);
            aM[tid] = mag * __cosf(ang);
            aM[64 + tid] = mag * __sinf(ang);
        }
    }
}

__global__ __launch_bounds__(256, 6)
void fftconv_main(const float* __restrict__ u, const char* __restrict__ ws,
                  float* __restrict__ out) {
    __shared__ __align__(16) _Float16 u16p[ROWS * ROWP];  // u chunks, fp16
    __shared__ __align__(16) _Float16 S16[ROWS * ROWP];   // S_in then entering sB

    const int tid = threadIdx.x;
    const int lane = tid & 63;
    const int wv = tid >> 6;
    const int hf = blockIdx.x & 1;           // which half of the sequence
    const int sq = blockIdx.x >> 1;          // sequence 0..4095
    const int h = sq & 255;
    const float* ub = u + (size_t)sq * 8192;
    float* yb = out + (size_t)sq * 8192;
    const int co = hf << 5;                  // first emit chunk (0 or 32)
    const int l0 = ((co << 7) - 1024) & 8191;

    // ---- stage 40 chunks of u -> fp16 (coalesced float4, circular) ----
#pragma unroll
    for (int i = 0; i < 5; ++i) {
        int e4 = i * 256 + tid;              // 0..1279 float4s
        int gl = (l0 + (e4 << 2)) & 8191;
        float4 v = *(const float4*)(ub + gl);
        int el = e4 << 2;
        int c = el >> 7, j = el & 127;
        half4v hv = { (_Float16)v.x, (_Float16)v.y, (_Float16)v.z, (_Float16)v.w };
        *(half4v*)&u16p[c * ROWP + j] = hv;
    }
    __syncthreads();

    const int mrow = (wv << 5) + (lane & 31);      // A row (pc / r)
    const int kh = (lane >> 5) << 3;               // k-offset within frag
    const int ncol = lane & 31;                    // B/C col
    const int r0 = (wv << 5) + ((lane >> 5) << 2); // C row base

    // ---- GEMM1: S_in[pc][i] = W * u, cols i in [0,32) and [8,40) (overlap benign) ----
    {
        const _Float16* Wg = (const _Float16*)(ws + A2_BYTES);
        floatx16 acc0 = {}; floatx16 acc1 = {};
#pragma unroll
        for (int s = 0; s < 8; ++s) {
            int k0 = (s << 4) + kh;
            half8 af = *(const half8*)(Wg + mrow * CM + k0);
            half8 b0 = *(const half8*)&u16p[ncol * ROWP + k0];
            half8 b1 = *(const half8*)&u16p[(8 + ncol) * ROWP + k0];
            acc0 = __builtin_amdgcn_mfma_f32_32x32x16_f16(af, b0, acc0, 0, 0, 0);
            acc1 = __builtin_amdgcn_mfma_f32_32x32x16_f16(af, b1, acc1, 0, 0, 0);
        }
#pragma unroll
        for (int g = 0; g < 4; ++g) {
            half4v h0 = { (_Float16)acc0[4 * g + 0], (_Float16)acc0[4 * g + 1],
                          (_Float16)acc0[4 * g + 2], (_Float16)acc0[4 * g + 3] };
            *(half4v*)&S16[ncol * ROWP + r0 + 8 * g] = h0;
            half4v h1 = { (_Float16)acc1[4 * g + 0], (_Float16)acc1[4 * g + 1],
                          (_Float16)acc1[4 * g + 2], (_Float16)acc1[4 * g + 3] };
            *(half4v*)&S16[(8 + ncol) * ROWP + r0 + 8 * g] = h1;
        }
    }
    __syncthreads();

    // ---- serial chunk-state scan (wave 0, lane = pole): 8 warm + 32 emit ----
    if (wv == 0) {
        const float* aM = (const float*)(ws + AM_OFF);
        const float amr = aM[lane], ami = aM[64 + lane];
        float sr = 0.f, si = 0.f;
#pragma unroll
        for (int c = 0; c < 8; ++c) {
            float xr = (float)S16[c * ROWP + lane];
            float xi = (float)S16[c * ROWP + 64 + lane];
            float nr = fmaf(amr, sr, fmaf(-ami, si, xr));
            float ni = fmaf(amr, si, fmaf(ami, sr, xi));
            sr = nr; si = ni;
        }
#pragma unroll
        for (int c = 8; c < ROWS; ++c) {
            float xr = (float)S16[c * ROWP + lane];
            float xi = (float)S16[c * ROWP + 64 + lane];
            S16[c * ROWP + lane] = (_Float16)sr;        // ENTERING state
            S16[c * ROWP + 64 + lane] = (_Float16)si;
            float nr = fmaf(amr, sr, fmaf(-ami, si, xr));
            float ni = fmaf(amr, si, fmaf(ami, sr, xi));
            sr = nr; si = ni;
        }
    }
    __syncthreads();

    // ---- GEMM2: y[r][i] = G*sB + T'*u over 32 emit cols, tanh, store ----
    {
        const _Float16* Ag = (const _Float16*)ws + ((size_t)h * CM + mrow) * 256;
        floatx16 acc = {};
#pragma unroll
        for (int s = 0; s < 8; ++s) {          // G * sB
            int k0 = (s << 4) + kh;
            half8 af = *(const half8*)(Ag + k0);
            half8 b = *(const half8*)&S16[(8 + ncol) * ROWP + k0];
            acc = __builtin_amdgcn_mfma_f32_32x32x16_f16(af, b, acc, 0, 0, 0);
        }
#pragma unroll
        for (int s = 0; s < 8; ++s) {          // T' * u
            int k0 = (s << 4) + kh;
            half8 af = *(const half8*)(Ag + CM + k0);
            half8 b = *(const half8*)&u16p[(8 + ncol) * ROWP + k0];
            acc = __builtin_amdgcn_mfma_f32_32x32x16_f16(af, b, acc, 0, 0, 0);
        }
        const int gc = co + ncol;              // global chunk
#pragma unroll
        for (int g = 0; g < 4; ++g) {
            float4 o;
            o.x = fast_tanh(acc[4 * g + 0]); o.y = fast_tanh(acc[4 * g + 1]);
            o.z = fast_tanh(acc[4 * g + 2]); o.w = fast_tanh(acc[4 * g + 3]);
            *(float4*)(yb + (size_t)gc * CM + r0 + 8 * g) = o;
        }
    }
}

extern "C" void kernel_launch(void* const* d_in, const int* in_sizes, int n_in,
                              void* d_out, int out_size, void* d_ws, size_t ws_size,
                              hipStream_t stream) {
    const float* u     = (const float*)d_in[0];
    const float* A_re  = (const float*)d_in[1];
    const float* A_im  = (const float*)d_in[2];
    const float* BC_re = (const float*)d_in[3];
    const float* BC_im = (const float*)d_in[4];
    const float* Dv    = (const float*)d_in[5];
    float* out = (float*)d_out;
    char* ws = (char*)d_ws;

    hipLaunchKernelGGL(fftconv_prep, dim3(256), dim3(256), 0, stream,
                       A_re, A_im, BC_re, BC_im, Dv, ws);
    hipLaunchKernelGGL(fftconv_main, dim3(8192), dim3(256), 0, stream,
                       u, ws, out);
}